// Round 5
// baseline (195.388 us; speedup 1.0000x reference)
//
#include <hip/hip_runtime.h>
#include <cstdint>
#include <cstddef>

#define NUM_LAYERS 20
#define HID 1024
#define M_TOTAL 8192

typedef __attribute__((ext_vector_type(8))) short bf16x8;
typedef __attribute__((ext_vector_type(4))) float floatx4;
typedef __attribute__((ext_vector_type(4))) float f32x4;
typedef __attribute__((ext_vector_type(8))) unsigned short u16x8;

typedef __attribute__((address_space(1))) unsigned int as1_u32;
typedef __attribute__((address_space(3))) unsigned int as3_u32;

__device__ __forceinline__ unsigned short f2bf(float f) {
  union { float f; unsigned int u; } v; v.f = f;
  unsigned int r = v.u + 0x7fffu + ((v.u >> 16) & 1u);  // RNE
  return (unsigned short)(r >> 16);
}

__device__ __forceinline__ float bf2f(unsigned short u) {
  union { unsigned int u; float f; } v; v.u = ((unsigned int)u) << 16;
  return v.f;
}

__device__ __forceinline__ u16x8 pack8(f32x4 a, f32x4 b) {
  u16x8 o;
  o[0] = f2bf(a[0]); o[1] = f2bf(a[1]); o[2] = f2bf(a[2]); o[3] = f2bf(a[3]);
  o[4] = f2bf(b[0]); o[5] = f2bf(b[1]); o[6] = f2bf(b[2]); o[7] = f2bf(b[3]);
  return o;
}

// async global->LDS, 16B/lane; LDS ptr must be wave-uniform base (HW adds lane*16)
__device__ __forceinline__ void load16_lds(const void* g, void* l) {
  __builtin_amdgcn_global_load_lds(
      reinterpret_cast<as1_u32*>(reinterpret_cast<uintptr_t>(g)),
      reinterpret_cast<as3_u32*>(reinterpret_cast<uintptr_t>(l)),
      16, 0, 0);
}

// ---- Kernel 1: fused prep (unchanged from R4 — it dropped below the fill time).
// Blocks 0..511:    conv_w 20-layer sum -> bf16 wb, 40 float4 loads in flight.
// Blocks 512..2559: x fp32->bf16, 4 float4 loads + 2 ushort8 stores / thread.
__global__ __launch_bounds__(256, 1) void prep_kernel(const float* __restrict__ x,
                                                      const float* __restrict__ w,
                                                      unsigned short* __restrict__ xb,
                                                      unsigned short* __restrict__ wb) {
  const int b = blockIdx.x;
  const int t = threadIdx.x;
  if (b < 512) {
    const int P = b * 256 + t;  // ushort8 output index; float4 pair (2P, 2P+1)
    const f32x4* p = reinterpret_cast<const f32x4*>(w);
    f32x4 va[NUM_LAYERS], vb[NUM_LAYERS];
#pragma unroll
    for (int l = 0; l < NUM_LAYERS; ++l) {
      const f32x4* pl = p + (size_t)l * (HID * HID / 4) + (size_t)2 * P;
      va[l] = __builtin_nontemporal_load(pl);
      vb[l] = __builtin_nontemporal_load(pl + 1);
    }
    f32x4 s0 = va[0], s1 = vb[0];
#pragma unroll
    for (int l = 1; l < NUM_LAYERS; ++l) { s0 += va[l]; s1 += vb[l]; }
    reinterpret_cast<u16x8*>(wb)[P] = pack8(s0, s1);
  } else {
    const int bb = b - 512;
#pragma unroll
    for (int j = 0; j < 2; ++j) {
      const int P = bb * 512 + t + j * 256;  // ushort8 output index
      const f32x4* p = reinterpret_cast<const f32x4*>(x) + (size_t)2 * P;
      f32x4 v0 = __builtin_nontemporal_load(p);
      f32x4 v1 = __builtin_nontemporal_load(p + 1);
      reinterpret_cast<u16x8*>(xb)[P] = pack8(v0, v1);
    }
  }
}

// ---- Kernel 2: GEMM C[M][N] = A[M][K] @ B[N][K]^T (raw, unscaled), bf16 out ----
// 128x64 tile (MxN), 128 threads = 2 waves, each wave 64x64 (4x4 of 16x16x32 MFMA).
// BK=64 as TWO sequential BK=32 sub-tiles: 12 staging issues + 32 MFMA/wave per
// barrier-pair (vs 6+16) -> half the vmcnt(0)+s_barrier drains (AITER-style
// ~32 MFMA/barrier). Two sub-tiles (not one strided 64-K tile) keep the
// conflict-free [row][32] LDS layout, since global_load_lds forbids padding.
// Frags are processed sub-tile-serially to stay under the 128-VGPR cap.
__global__ __launch_bounds__(128, 4) void gemm_kernel(const unsigned short* __restrict__ A,
                                                      const unsigned short* __restrict__ B,
                                                      unsigned short* __restrict__ Cb) {
  __shared__ unsigned short lA[2][128 * 32];  // 16 KiB
  __shared__ unsigned short lB[2][64 * 32];   // 8 KiB

  const int tid = threadIdx.x;
  const int lane = tid & 63;
  const int w = tid >> 6;      // wave 0..1 -> M halves
  const int quad = lane >> 4;  // 0..3
  const int mrow = lane & 15;

  const int bid = blockIdx.x;
  const int nb = bid & 15;  // 16 N-tiles inner -> consecutive blocks share A tile (L2)
  const int mb = bid >> 4;  // 64 M-tiles

  const int srow = tid >> 2;          // 0..31
  const int skoff = (tid & 3) * 8;
  const unsigned short* gA = A + (size_t)(mb * 128 + srow) * HID + skoff;
  const unsigned short* gB = B + (size_t)(nb * 64 + srow) * HID + skoff;

  floatx4 acc[4][4] = {};

  // fragment read offsets (ushort units, relative to lA[s] / lB[s])
  int raOff[4], rbOff[4];
#pragma unroll
  for (int i = 0; i < 4; ++i)
    raOff[i] = (w * 64 + i * 16 + mrow) * 32 + quad * 8;
#pragma unroll
  for (int j = 0; j < 4; ++j)
    rbOff[j] = (j * 16 + mrow) * 32 + quad * 8;

  for (int k0 = 0; k0 < HID; k0 += 64) {
    __syncthreads();  // prior iter's ds_reads done before overwrite
    // sub-tile 0: k[k0, k0+32)
    load16_lds(gA,                    lA[0] + w * 512);
    load16_lds(gA + (size_t)32 * HID, lA[0] + w * 512 + 1024);
    load16_lds(gA + (size_t)64 * HID, lA[0] + w * 512 + 2048);
    load16_lds(gA + (size_t)96 * HID, lA[0] + w * 512 + 3072);
    load16_lds(gB,                    lB[0] + w * 512);
    load16_lds(gB + (size_t)32 * HID, lB[0] + w * 512 + 1024);
    // sub-tile 1: k[k0+32, k0+64)
    load16_lds(gA + 32,                    lA[1] + w * 512);
    load16_lds(gA + 32 + (size_t)32 * HID, lA[1] + w * 512 + 1024);
    load16_lds(gA + 32 + (size_t)64 * HID, lA[1] + w * 512 + 2048);
    load16_lds(gA + 32 + (size_t)96 * HID, lA[1] + w * 512 + 3072);
    load16_lds(gB + 32,                    lB[1] + w * 512);
    load16_lds(gB + 32 + (size_t)32 * HID, lB[1] + w * 512 + 1024);
    gA += 64;
    gB += 64;
    __syncthreads();  // staging visible (compiler drains vmcnt before barrier)

#pragma unroll
    for (int s = 0; s < 2; ++s) {
      bf16x8 af[4], bfr[4];
#pragma unroll
      for (int i = 0; i < 4; ++i) af[i] = *reinterpret_cast<const bf16x8*>(lA[s] + raOff[i]);
#pragma unroll
      for (int j = 0; j < 4; ++j) bfr[j] = *reinterpret_cast<const bf16x8*>(lB[s] + rbOff[j]);
#pragma unroll
      for (int i = 0; i < 4; ++i)
#pragma unroll
        for (int j = 0; j < 4; ++j)
          acc[i][j] = __builtin_amdgcn_mfma_f32_16x16x32_bf16(af[i], bfr[j], acc[i][j], 0, 0, 0);
    }
  }

  // epilogue: C/D layout col=lane&15, row=quad*4+reg. Store raw dot as bf16.
  const int row_base = mb * 128 + w * 64 + quad * 4;
  const int col_base = nb * 64 + mrow;
#pragma unroll
  for (int i = 0; i < 4; ++i) {
#pragma unroll
    for (int j = 0; j < 4; ++j) {
#pragma unroll
      for (int r = 0; r < 4; ++r) {
        int row = row_base + i * 16 + r;
        Cb[(size_t)row * HID + col_base + j * 16] = f2bf(acc[i][j][r]);
      }
    }
  }
}

// ---- Kernel 3: RMS norm, one WAVE per row; ushort8 loads, NT float4 stores ----
// out = C * 32 * rsqrt(sum C^2 + 400*eps*H) * norm_w   (/20 folded into scale)
__global__ __launch_bounds__(256) void rmsnorm_kernel(const unsigned short* __restrict__ Cb,
                                                      const float* __restrict__ nw,
                                                      float* __restrict__ out) {
  const int row = blockIdx.x * 4 + (threadIdx.x >> 6);
  const int lane = threadIdx.x & 63;
  const u16x8* src = reinterpret_cast<const u16x8*>(Cb) + (size_t)row * 128;
  f32x4 v[2][2];
  float ss = 0.f;
#pragma unroll
  for (int j = 0; j < 2; ++j) {
    u16x8 u = src[lane + j * 64];
#pragma unroll
    for (int h = 0; h < 2; ++h) {
#pragma unroll
      for (int e = 0; e < 4; ++e) {
        float f = bf2f(u[h * 4 + e]);
        v[j][h][e] = f;
        ss += f * f;
      }
    }
  }
#pragma unroll
  for (int off = 32; off > 0; off >>= 1) ss += __shfl_xor(ss, off, 64);
  const float scale = 32.0f * rsqrtf(ss + 0.4096f);  // 32=sqrt(H); 0.4096 = eps*H*400
  const f32x4* nwp = reinterpret_cast<const f32x4*>(nw);
  f32x4* dst = reinterpret_cast<f32x4*>(out) + (size_t)row * 256;
#pragma unroll
  for (int j = 0; j < 2; ++j) {
#pragma unroll
    for (int h = 0; h < 2; ++h) {
      const int fi = 2 * (lane + j * 64) + h;
      f32x4 wv = nwp[fi];
      f32x4 o = v[j][h] * scale * wv;
      __builtin_nontemporal_store(o, dst + fi);
    }
  }
}

extern "C" void kernel_launch(void* const* d_in, const int* in_sizes, int n_in,
                              void* d_out, int out_size, void* d_ws, size_t ws_size,
                              hipStream_t stream) {
  const float* x = (const float*)d_in[0];       // [2,4096,1024] fp32
  const float* conv_w = (const float*)d_in[1];  // [20,1024,1024] fp32
  const float* norm_w = (const float*)d_in[2];  // [1024] fp32
  float* out = (float*)d_out;                   // [2,4096,1024] fp32

  unsigned short* xb = (unsigned short*)d_ws;       // 16 MiB: A bf16
  unsigned short* wb = xb + (size_t)M_TOTAL * HID;  // +2 MiB: summed W bf16 ([N][K])
  unsigned short* cb = wb + (size_t)HID * HID;      // +16 MiB: C bf16

  prep_kernel<<<512 + 2048, 256, 0, stream>>>(x, conv_w, xb, wb);
  gemm_kernel<<<(M_TOTAL / 128) * (HID / 64), 128, 0, stream>>>(xb, wb, cb);
  rmsnorm_kernel<<<M_TOTAL / 4, 256, 0, stream>>>(cb, norm_w, out);
}